// Round 1
// baseline (1078.259 us; speedup 1.0000x reference)
//
#include <hip/hip_runtime.h>

// KNN (k=5, LARGEST distances per faithful-to-source quirk) + gather-mean.
// x: [B=2048, 64] f32, target: [N=50000, 64] f32, out: [B, 64] f32.

constexpr int KNN = 5;
constexpr int DD  = 64;   // feature dim
constexpr int QB  = 64;   // queries per block (kernel B)
constexpr int TQ  = 8;    // queries per wave
constexpr int NT  = 256;  // targets per tile
constexpr int KC  = 16;   // d-depth per staged chunk
constexpr int CH  = 16;   // target chunks (grid.x of kernel B)
constexpr int BLK = 512;  // threads in kernel B

// rank (ad,ai) above (bd,bi): larger dist^2 first, tie -> smaller index
__device__ __forceinline__ bool pair_gt(float ad, int ai, float bd, int bi) {
  return (ad > bd) || (ad == bd && ai < bi);
}

// Branchless sorted insert into a descending top-5 (caller guarantees the
// candidate ranks above slot 4). All slot reads happen before overwrite.
__device__ __forceinline__ void top5_insert(float d2, int idx,
    float& t0d, float& t1d, float& t2d, float& t3d, float& t4d,
    int&   t0i, int&   t1i, int&   t2i, int&   t3i, int&   t4i) {
  const bool b3 = pair_gt(d2, idx, t3d, t3i);
  const bool b2 = pair_gt(d2, idx, t2d, t2i);
  const bool b1 = pair_gt(d2, idx, t1d, t1i);
  const bool b0 = pair_gt(d2, idx, t0d, t0i);
  t4d = b3 ? t3d : d2;               t4i = b3 ? t3i : idx;
  t3d = b3 ? (b2 ? t2d : d2) : t3d;  t3i = b3 ? (b2 ? t2i : idx) : t3i;
  t2d = b2 ? (b1 ? t1d : d2) : t2d;  t2i = b2 ? (b1 ? t1i : idx) : t2i;
  t1d = b1 ? (b0 ? t0d : d2) : t1d;  t1i = b1 ? (b0 ? t0i : idx) : t1i;
  t0d = b0 ? d2 : t0d;               t0i = b0 ? idx : t0i;
}

// ---------------- Kernel A: per-target squared norm ----------------
__launch_bounds__(256)
__global__ void sqnorm_kernel(const float* __restrict__ tg,
                              float* __restrict__ t2, int N) {
  const int tid  = threadIdx.x;
  const int lane = tid & 63;
  const int wv   = tid >> 6;
  const int row  = blockIdx.x * 16 + wv * 4 + (lane >> 4);
  const int f4   = lane & 15;
  if (row >= N) return;
  const float4 v = reinterpret_cast<const float4*>(tg)[(size_t)row * 16 + f4];
  float s = v.x*v.x + v.y*v.y + v.z*v.z + v.w*v.w;
  s += __shfl_xor(s, 1);
  s += __shfl_xor(s, 2);
  s += __shfl_xor(s, 4);
  s += __shfl_xor(s, 8);
  if (f4 == 0) t2[row] = s;
}

// ---------------- Kernel B: distances + per-(query,chunk) top-5 ----------------
__launch_bounds__(BLK, 2)
__global__ void knn_partial_kernel(const float* __restrict__ x,
                                   const float* __restrict__ tg,
                                   const float* __restrict__ t2w,
                                   float* __restrict__ pd,
                                   int*   __restrict__ pi,
                                   int N) {
  __shared__ float tbuf[2][KC][NT];  // 32 KiB, d-major target tile, double-buffered
  __shared__ float t2s[2][NT];       // 2 KiB, tile-parity buffered

  const int tid  = threadIdx.x;
  const int lane = tid & 63;
  const int w    = __builtin_amdgcn_readfirstlane(tid >> 6);  // wave id, uniform
  const int ci   = blockIdx.x;                                // target chunk
  const int q0   = blockIdx.y * QB + w * TQ;                  // wave's first query

  // ---- ||x||^2 for this wave's 8 queries (8 lanes per query) ----
  float x2[TQ];
  {
    const int qi  = lane >> 3;
    const int sub = lane & 7;
    const float4* xr = reinterpret_cast<const float4*>(x) + (size_t)(q0 + qi) * (DD / 4);
    const float4 a = xr[sub * 2];
    const float4 b = xr[sub * 2 + 1];
    float s = a.x*a.x + a.y*a.y + a.z*a.z + a.w*a.w
            + b.x*b.x + b.y*b.y + b.z*b.z + b.w*b.w;
    s += __shfl_xor(s, 1);
    s += __shfl_xor(s, 2);
    s += __shfl_xor(s, 4);
    #pragma unroll
    for (int k = 0; k < TQ; ++k) x2[k] = __shfl(s, k * 8);
  }

  // per-thread top-5 per query (descending)
  float td0[TQ], td1[TQ], td2[TQ], td3[TQ], td4[TQ];
  int   ti0[TQ], ti1[TQ], ti2[TQ], ti3[TQ], ti4[TQ];
  #pragma unroll
  for (int qi = 0; qi < TQ; ++qi) {
    td0[qi]=td1[qi]=td2[qi]=td3[qi]=td4[qi] = -1e30f;
    ti0[qi]=ti1[qi]=ti2[qi]=ti3[qi]=ti4[qi] = 0;
  }

  float acc[TQ][4];

  const int total_tiles = (N + NT - 1) / NT;
  const int mytiles = (ci < total_tiles) ? ((total_tiles - 1 - ci) / CH + 1) : 0;
  const int C = mytiles * 4;  // chunk iterations

  // staging registers (T14 issue-early / write-late split)
  float4 sva = make_float4(0,0,0,0), svb = make_float4(0,0,0,0);
  float  t2r = 0.0f;
  const int n0  = tid & 255;          // this thread's target row in tile
  const int j40 = tid >> 8;           // float4 slot 0..1
  const int j41 = ((tid + BLK) >> 8); // float4 slot 2..3
  const float4* tgv = reinterpret_cast<const float4*>(tg);

  // ---- prologue: stage chunk 0 ----
  if (C > 0) {
    const long r0 = (long)ci * NT + n0;
    if (r0 < N) {
      sva = tgv[r0 * 16 + j40];
      svb = tgv[r0 * 16 + j41];
      if (tid < NT) t2r = t2w[r0];
    }
    tbuf[0][j40*4+0][n0] = sva.x;  tbuf[0][j40*4+1][n0] = sva.y;
    tbuf[0][j40*4+2][n0] = sva.z;  tbuf[0][j40*4+3][n0] = sva.w;
    tbuf[0][j41*4+0][n0] = svb.x;  tbuf[0][j41*4+1][n0] = svb.y;
    tbuf[0][j41*4+2][n0] = svb.z;  tbuf[0][j41*4+3][n0] = svb.w;
    if (tid < NT) t2s[0][tid] = t2r;
  }
  __syncthreads();

  for (int c = 0; c < C; ++c) {
    const int b       = c & 1;
    const int kc      = c & 3;
    const int tileidx = ci + (c >> 2) * CH;
    const bool more   = (c + 1 < C);

    // 1) issue global loads for chunk c+1 (latency hides under compute)
    int kc2 = 0;
    if (more) {
      const int gc2   = c + 1;
      kc2             = gc2 & 3;
      const int tile2 = ci + (gc2 >> 2) * CH;
      const long r0n  = (long)tile2 * NT + n0;
      sva = make_float4(0,0,0,0);
      svb = make_float4(0,0,0,0);
      if (r0n < N) {
        sva = tgv[r0n * 16 + kc2 * 4 + j40];
        svb = tgv[r0n * 16 + kc2 * 4 + j41];
      }
      if (kc2 == 0) t2r = (tid < NT && r0n < N) ? t2w[r0n] : 0.0f;
    }

    // 2) compute chunk c
    if (kc == 0) {
      #pragma unroll
      for (int qi = 0; qi < TQ; ++qi) {
        acc[qi][0]=0.f; acc[qi][1]=0.f; acc[qi][2]=0.f; acc[qi][3]=0.f;
      }
    }
    #pragma unroll
    for (int h = 0; h < 2; ++h) {
      // wave-uniform query fragment (8 q x 8 d) -> scalar regs (hopefully s_load)
      float qsv[TQ][8];
      const float* xp = x + (size_t)q0 * DD + (kc * KC + h * 8);
      #pragma unroll
      for (int qi = 0; qi < TQ; ++qi) {
        #pragma unroll
        for (int dd = 0; dd < 8; ++dd) qsv[qi][dd] = xp[qi * DD + dd];
      }
      #pragma unroll
      for (int dd = 0; dd < 8; ++dd) {
        const float4 tv = *reinterpret_cast<const float4*>(&tbuf[b][h*8+dd][lane*4]);
        const float ta0 = tv.x, ta1 = tv.y, ta2 = tv.z, ta3 = tv.w;
        #pragma unroll
        for (int qi = 0; qi < TQ; ++qi) {
          acc[qi][0] = fmaf(qsv[qi][dd], ta0, acc[qi][0]);
          acc[qi][1] = fmaf(qsv[qi][dd], ta1, acc[qi][1]);
          acc[qi][2] = fmaf(qsv[qi][dd], ta2, acc[qi][2]);
          acc[qi][3] = fmaf(qsv[qi][dd], ta3, acc[qi][3]);
        }
      }
    }

    // 3) tile epilogue: d2 = x2 + t2 - 2*dot, update top-5
    if (kc == 3) {
      const int tp = (c >> 2) & 1;
      const int nb = tileidx * NT + lane * 4;
      const float t2a[4] = { t2s[tp][lane*4+0], t2s[tp][lane*4+1],
                             t2s[tp][lane*4+2], t2s[tp][lane*4+3] };
      #pragma unroll
      for (int qi = 0; qi < TQ; ++qi) {
        const float xq = x2[qi];
        #pragma unroll
        for (int j = 0; j < 4; ++j) {
          const float d2  = fmaf(-2.0f, acc[qi][j], xq + t2a[j]);
          const int   idx = nb + j;
          if (idx < N && pair_gt(d2, idx, td4[qi], ti4[qi]))
            top5_insert(d2, idx,
                        td0[qi], td1[qi], td2[qi], td3[qi], td4[qi],
                        ti0[qi], ti1[qi], ti2[qi], ti3[qi], ti4[qi]);
        }
      }
    }

    // 4) write staged chunk c+1 into the other buffer
    if (more) {
      const int bo = (c + 1) & 1;
      tbuf[bo][j40*4+0][n0] = sva.x;  tbuf[bo][j40*4+1][n0] = sva.y;
      tbuf[bo][j40*4+2][n0] = sva.z;  tbuf[bo][j40*4+3][n0] = sva.w;
      tbuf[bo][j41*4+0][n0] = svb.x;  tbuf[bo][j41*4+1][n0] = svb.y;
      tbuf[bo][j41*4+2][n0] = svb.z;  tbuf[bo][j41*4+3][n0] = svb.w;
      if (kc2 == 0 && tid < NT) t2s[((c + 1) >> 2) & 1][tid] = t2r;
    }
    __syncthreads();
  }

  // ---- cross-lane merge: wave top-5 per query, write partials ----
  #pragma unroll
  for (int qi = 0; qi < TQ; ++qi) {
    float rd[KNN]; int ri[KNN];
    #pragma unroll
    for (int r = 0; r < KNN; ++r) {
      float md = td0[qi]; int mi = ti0[qi];
      #pragma unroll
      for (int k = 1; k < 64; k <<= 1) {
        const float od = __shfl_xor(md, k);
        const int   oi = __shfl_xor(mi, k);
        if (pair_gt(od, oi, md, mi)) { md = od; mi = oi; }
      }
      rd[r] = md; ri[r] = mi;
      if (ti0[qi] == mi && td0[qi] == md) {  // consume winner (indices unique)
        td0[qi]=td1[qi]; ti0[qi]=ti1[qi];
        td1[qi]=td2[qi]; ti1[qi]=ti2[qi];
        td2[qi]=td3[qi]; ti2[qi]=ti3[qi];
        td3[qi]=td4[qi]; ti3[qi]=ti4[qi];
        td4[qi]=-1e30f;  ti4[qi]=0;
      }
    }
    if (lane == 0) {
      const int pbase = (q0 + qi) * (CH * KNN) + ci * KNN;
      #pragma unroll
      for (int r = 0; r < KNN; ++r) { pd[pbase + r] = rd[r]; pi[pbase + r] = ri[r]; }
    }
  }
}

// ---------------- Kernel C: merge partials, gather, mean ----------------
__launch_bounds__(64)
__global__ void merge_kernel(const float* __restrict__ tg,
                             const float* __restrict__ pd,
                             const int*   __restrict__ pi,
                             float* __restrict__ out, int chn) {
  const int q    = blockIdx.x;
  const int lane = threadIdx.x;   // 64 threads
  const int M    = chn * KNN;     // 80 candidates
  const int pb   = q * M;
  float c0d = -1e30f, c1d = -1e30f;
  int   c0i = 0,      c1i = 0;
  if (lane < M)      { c0d = pd[pb + lane];      c0i = pi[pb + lane]; }
  if (lane + 64 < M) { c1d = pd[pb + lane + 64]; c1i = pi[pb + lane + 64]; }
  if (pair_gt(c1d, c1i, c0d, c0i)) {
    const float tdm = c0d; const int tim = c0i;
    c0d = c1d; c0i = c1i; c1d = tdm; c1i = tim;
  }
  int sel[KNN];
  #pragma unroll
  for (int r = 0; r < KNN; ++r) {
    float md = c0d; int mi = c0i;
    #pragma unroll
    for (int k = 1; k < 64; k <<= 1) {
      const float od = __shfl_xor(md, k);
      const int   oi = __shfl_xor(mi, k);
      if (pair_gt(od, oi, md, mi)) { md = od; mi = oi; }
    }
    sel[r] = mi;
    if (c0i == mi && c0d == md) { c0d = c1d; c0i = c1i; c1d = -1e30f; c1i = 0; }
  }
  float s = 0.0f;
  #pragma unroll
  for (int r = 0; r < KNN; ++r) s += tg[(size_t)sel[r] * DD + lane];
  out[(size_t)q * DD + lane] = s / 5.0f;
}

// ---------------- Fallback (only if workspace too small) ----------------
__launch_bounds__(256)
__global__ void knn_fallback(const float* __restrict__ x,
                             const float* __restrict__ tg,
                             float* __restrict__ out, int N) {
  const int q   = blockIdx.x;
  const int tid = threadIdx.x;
  __shared__ float qsh[DD];
  __shared__ float smd[KNN][256];
  __shared__ int   smi[KNN][256];
  if (tid < DD) qsh[tid] = x[(size_t)q * DD + tid];
  __syncthreads();
  float qv[DD];
  #pragma unroll
  for (int d = 0; d < DD; ++d) qv[d] = qsh[d];
  float x2 = 0.0f;
  #pragma unroll
  for (int d = 0; d < DD; ++d) x2 = fmaf(qv[d], qv[d], x2);
  float a0=-1e30f,a1=-1e30f,a2=-1e30f,a3=-1e30f,a4=-1e30f;
  int   i0=0,i1=0,i2=0,i3=0,i4=0;
  for (int n = tid; n < N; n += 256) {
    const float4* tr = reinterpret_cast<const float4*>(tg + (size_t)n * DD);
    float dot = 0.0f, tt = 0.0f;
    #pragma unroll
    for (int k = 0; k < 16; ++k) {
      const float4 tv = tr[k];
      dot = fmaf(qv[4*k+0], tv.x, dot); tt = fmaf(tv.x, tv.x, tt);
      dot = fmaf(qv[4*k+1], tv.y, dot); tt = fmaf(tv.y, tv.y, tt);
      dot = fmaf(qv[4*k+2], tv.z, dot); tt = fmaf(tv.z, tv.z, tt);
      dot = fmaf(qv[4*k+3], tv.w, dot); tt = fmaf(tv.w, tv.w, tt);
    }
    const float d2 = fmaf(-2.0f, dot, x2 + tt);
    if (pair_gt(d2, n, a4, i4))
      top5_insert(d2, n, a0,a1,a2,a3,a4, i0,i1,i2,i3,i4);
  }
  smd[0][tid]=a0; smi[0][tid]=i0;  smd[1][tid]=a1; smi[1][tid]=i1;
  smd[2][tid]=a2; smi[2][tid]=i2;  smd[3][tid]=a3; smi[3][tid]=i3;
  smd[4][tid]=a4; smi[4][tid]=i4;
  __syncthreads();
  if (tid < 64) {
    a0=a1=a2=a3=a4=-1e30f; i0=i1=i2=i3=i4=0;
    for (int src = tid; src < 256; src += 64) {
      #pragma unroll
      for (int r = 0; r < KNN; ++r) {
        const float dd2 = smd[r][src]; const int ii = smi[r][src];
        if (pair_gt(dd2, ii, a4, i4))
          top5_insert(dd2, ii, a0,a1,a2,a3,a4, i0,i1,i2,i3,i4);
      }
    }
    int sel[KNN];
    #pragma unroll
    for (int r = 0; r < KNN; ++r) {
      float md = a0; int mi = i0;
      #pragma unroll
      for (int k = 1; k < 64; k <<= 1) {
        const float od = __shfl_xor(md, k);
        const int   oi = __shfl_xor(mi, k);
        if (pair_gt(od, oi, md, mi)) { md = od; mi = oi; }
      }
      sel[r] = mi;
      if (i0 == mi && a0 == md) {
        a0=a1; i0=i1; a1=a2; i1=i2; a2=a3; i2=i3; a3=a4; i3=i4; a4=-1e30f; i4=0;
      }
    }
    float s = 0.0f;
    #pragma unroll
    for (int r = 0; r < KNN; ++r) s += tg[(size_t)sel[r] * DD + tid];
    out[(size_t)q * DD + tid] = s / 5.0f;
  }
}

extern "C" void kernel_launch(void* const* d_in, const int* in_sizes, int n_in,
                              void* d_out, int out_size, void* d_ws, size_t ws_size,
                              hipStream_t stream) {
  const float* x  = (const float*)d_in[0];
  const float* tg = (const float*)d_in[1];
  float* out = (float*)d_out;
  const int B = in_sizes[0] / DD;   // 2048
  const int N = in_sizes[1] / DD;   // 50000

  const size_t t2_elems = ((size_t)N + 127) & ~(size_t)127;
  const size_t npart    = (size_t)B * CH * KNN;
  const size_t need     = (t2_elems + 2 * npart) * sizeof(float);

  if (ws_size >= need && (B % QB) == 0) {
    float* t2 = (float*)d_ws;
    float* pd = t2 + t2_elems;
    int*   pi = (int*)(pd + npart);
    sqnorm_kernel<<<dim3((N + 15) / 16), dim3(256), 0, stream>>>(tg, t2, N);
    knn_partial_kernel<<<dim3(CH, B / QB), dim3(BLK), 0, stream>>>(x, tg, t2, pd, pi, N);
    merge_kernel<<<dim3(B), dim3(64), 0, stream>>>(tg, pd, pi, out, CH);
  } else {
    knn_fallback<<<dim3(B), dim3(256), 0, stream>>>(x, tg, out, N);
  }
}